// Round 12
// baseline (281.001 us; speedup 1.0000x reference)
//
#include <hip/hip_runtime.h>
#include <hip/hip_bf16.h>

#define NODE_DIM 256
#define COND_DIM 512
#define OUT_DIM  128
#define HID      64
#define LN_EPS   1e-5f

// dst-bin partition: windows of 128 nodes -> nbin = ceil(N/128) (=782)
#define BIN_SHIFT 7
#define WINDOW    128
#define MAXBIN    1024

// fixed-capacity bins: no prefix scan needed. mean fill 2048, sd ~45 over
// 782 bins -> CAP=4096 is ~45 sigma of headroom. part = MAXBIN*CAP*4B = 16MB.
#define BIN_CAP   4096

// part entry packed: (local_row << 20) | src   (src < 2^17, local_row < 128)
#define PACK_SHIFT 20
#define SRC_MASK   0xFFFFF

// h stored fixed-point ushort (x512). LDS accumulator is u64 per feat-pair:
// low 32 = sum(feat even) + deg<<23, high 32 = sum(feat odd).
// All-int LDS atomics only (fp LDS atomic = CAS loop, round-3 lesson: 696us).
#define H_SCALE   512.f
#define DEG_BIT   23
#define SUM_MASK  ((1 << DEG_BIT) - 1)

typedef __attribute__((ext_vector_type(8))) short bf16x8;
typedef __attribute__((ext_vector_type(4))) float f32x4;

__device__ __forceinline__ short f2bf(float f) {
    __hip_bfloat16 h = __float2bfloat16(f);
    return *reinterpret_cast<short*>(&h);
}

// ---------------------------------------------------------------------------
// prep (grid 130):
//  blocks 0..127 : cond projection output o (weight-normed) -> gamma/beta
//  block 128     : weight-norm lin_w_v rows -> wlin_bf [128 o][64 k] bf16
//  block 129     : film_w -> fw_bf [64 h][256 k] bf16 ; zero bin_fill
// ---------------------------------------------------------------------------
__global__ __launch_bounds__(256) void prep(
    const float* __restrict__ cond_feats,
    const float* __restrict__ cond_w_v,
    const float* __restrict__ cond_w_g,
    const float* __restrict__ cond_b,
    const float* __restrict__ lin_w_v,
    const float* __restrict__ lin_w_g,
    const float* __restrict__ film_w,
    float* __restrict__ gamma, float* __restrict__ beta,
    short* __restrict__ wlin_bf, short* __restrict__ fw_bf,
    int* __restrict__ bin_fill, int N, int B)
{
    const int t = threadIdx.x;
    const int bid = blockIdx.x;
    if (bid == 128) {
        if (t < OUT_DIM) {
            const int o = t;
            float nrm = 0.f;
            float w[HID];
            #pragma unroll
            for (int k = 0; k < HID; ++k) {
                w[k] = lin_w_v[o * HID + k];
                nrm += w[k] * w[k];
            }
            const float s = lin_w_g[o] * rsqrtf(nrm);
            #pragma unroll
            for (int k = 0; k < HID; ++k) wlin_bf[o * HID + k] = f2bf(w[k] * s);
        }
        return;
    }
    if (bid == 129) {
        #pragma unroll
        for (int s = 0; s < MAXBIN / 256; ++s) bin_fill[t + s * 256] = 0;
        for (int idx = t; idx < HID * NODE_DIM; idx += 256)
            fw_bf[idx] = f2bf(film_w[idx]);
        return;
    }
    const int o = bid;
    const int lane = t & 63;
    const int wv = t >> 6;
    __shared__ float s_cp[64];
    __shared__ float s_nrm;
    float wreg[COND_DIM / 64];
    #pragma unroll
    for (int j = 0; j < COND_DIM / 64; ++j)
        wreg[j] = cond_w_v[o * COND_DIM + j * 64 + lane];
    float nr = 0.f;
    #pragma unroll
    for (int j = 0; j < COND_DIM / 64; ++j) nr += wreg[j] * wreg[j];
    #pragma unroll
    for (int off = 32; off > 0; off >>= 1) nr += __shfl_xor(nr, off, 64);
    if (t == 0) s_nrm = nr;
    for (int b = wv; b < 64; b += 4) {
        float a = 0.f;
        #pragma unroll
        for (int j = 0; j < COND_DIM / 64; ++j)
            a += wreg[j] * cond_feats[b * COND_DIM + j * 64 + lane];
        #pragma unroll
        for (int off = 32; off > 0; off >>= 1) a += __shfl_xor(a, off, 64);
        if (lane == 0) s_cp[b] = a;
    }
    __syncthreads();
    if (t < 64) {
        const float scale = cond_w_g[o] * rsqrtf(s_nrm);
        const float cp = scale * s_cp[t] + cond_b[o];
        if (o < HID) gamma[t * HID + o] = cp + 1.0f;
        else         beta[t * HID + (o - HID)] = cp;
    }
}

// ---------------------------------------------------------------------------
// fused_phase1 v7: 512-thread blocks, role split.
//  scatter blocks (G_scat = E/8192): LDS hist -> one returning atomic per
//    (block,bin) -> scatter packed (dl<<20|src) into part[bin*CAP...].
//  film blocks: 128 nodes per block (2x v6). fw_bf staged in LDS once per
//    128 nodes (halves staging traffic); 8 waves/block x 4 blocks/CU = 32
//    waves/CU (2x v6's 16) to hide the A-load L3 latency chain.
// ---------------------------------------------------------------------------
__global__ __launch_bounds__(512) void fused_phase1(
    const float* __restrict__ nf,
    const short* __restrict__ fw_bf,      // [64 h][256 k]
    const float* __restrict__ film_b,
    const float* __restrict__ gamma, const float* __restrict__ beta,
    const int*  __restrict__ n2g,
    unsigned short* __restrict__ h_out,   // [N][64] fixed-point x512
    const int* __restrict__ ei,
    int* __restrict__ bin_fill,
    int* __restrict__ part,
    int N, int E, int G_scat)
{
    __shared__ int smem[8192];            // 32 KB, aliased per role
    const int t = threadIdx.x;
    const int bid = blockIdx.x;

    if (bid < G_scat) {
        // ---------------- scatter block: 8192 edges, 512 threads ---------
        int* hist      = smem;            // [1024]
        int* chunkbase = smem + 1024;     // [1024]
        int* cursor    = smem + 2048;     // [1024]
        #pragma unroll
        for (int s = 0; s < 2; ++s) {
            hist[t + s * 512] = 0;
            cursor[t + s * 512] = 0;
        }
        const int base = bid * 8192;

        int4 dr[4];
        bool full[4];
        #pragma unroll
        for (int j = 0; j < 4; ++j) {
            const int e0 = base + j * 2048 + t * 4;
            full[j] = (e0 + 3 < E);
            if (full[j]) dr[j] = *(const int4*)(ei + E + e0);
        }
        __syncthreads();

        #pragma unroll
        for (int j = 0; j < 4; ++j) {
            if (full[j]) {
                atomicAdd(&hist[dr[j].x >> BIN_SHIFT], 1);
                atomicAdd(&hist[dr[j].y >> BIN_SHIFT], 1);
                atomicAdd(&hist[dr[j].z >> BIN_SHIFT], 1);
                atomicAdd(&hist[dr[j].w >> BIN_SHIFT], 1);
            } else {
                const int e0 = base + j * 2048 + t * 4;
                for (int k = 0; k < 4; ++k) {
                    const int e = e0 + k;
                    if (e < E) atomicAdd(&hist[ei[E + e] >> BIN_SHIFT], 1);
                }
            }
        }
        __syncthreads();
        #pragma unroll
        for (int s = 0; s < 2; ++s) {
            const int x = t + s * 512;
            const int c = hist[x];
            chunkbase[x] = (c > 0) ? atomicAdd(&bin_fill[x], c) : 0;
        }
        __syncthreads();

        #pragma unroll
        for (int j = 0; j < 4; ++j) {
            const int e0 = base + j * 2048 + t * 4;
            if (full[j]) {
                const int4 d4 = dr[j];
                const int4 s4 = *(const int4*)(ei + e0);
                int b, r;
                b = d4.x >> BIN_SHIFT; r = chunkbase[b] + atomicAdd(&cursor[b], 1);
                if (r < BIN_CAP) part[b * BIN_CAP + r] = ((d4.x & (WINDOW - 1)) << PACK_SHIFT) | s4.x;
                b = d4.y >> BIN_SHIFT; r = chunkbase[b] + atomicAdd(&cursor[b], 1);
                if (r < BIN_CAP) part[b * BIN_CAP + r] = ((d4.y & (WINDOW - 1)) << PACK_SHIFT) | s4.y;
                b = d4.z >> BIN_SHIFT; r = chunkbase[b] + atomicAdd(&cursor[b], 1);
                if (r < BIN_CAP) part[b * BIN_CAP + r] = ((d4.z & (WINDOW - 1)) << PACK_SHIFT) | s4.z;
                b = d4.w >> BIN_SHIFT; r = chunkbase[b] + atomicAdd(&cursor[b], 1);
                if (r < BIN_CAP) part[b * BIN_CAP + r] = ((d4.w & (WINDOW - 1)) << PACK_SHIFT) | s4.w;
            } else {
                for (int k = 0; k < 4; ++k) {
                    const int e = e0 + k;
                    if (e < E) {
                        const int d = ei[E + e];
                        const int b = d >> BIN_SHIFT;
                        const int r = chunkbase[b] + atomicAdd(&cursor[b], 1);
                        if (r < BIN_CAP)
                            part[b * BIN_CAP + r] =
                                ((d & (WINDOW - 1)) << PACK_SHIFT) | ei[e];
                    }
                }
            }
        }
        return;
    }

    // ---------------- film block: 128 nodes, 8 waves ---------------------
    unsigned short* fwL = (unsigned short*)smem;   // [64][256] bf16, swizzled
    const int film_id = bid - G_scat;
    const int n0 = film_id * 128;
    if (n0 >= N) return;

    // stage fw_bf -> LDS: 2048 16B chunks over 512 threads, XOR swizzle
    #pragma unroll
    for (int i = 0; i < 4; ++i) {
        const int g = i * 512 + t;            // global chunk id
        const int row = g >> 5;
        const int cc = g & 31;
        const int p = cc ^ ((row & 7) << 2);  // physical chunk
        *(bf16x8*)(fwL + row * 256 + p * 8) =
            *(const bf16x8*)(fw_bf + row * 256 + cc * 8);
    }
    __syncthreads();

    const int w = t >> 6;                    // wave 0..7 -> 16-row tile
    const int lane = t & 63;
    const int c = lane & 15;
    const int quad = lane >> 4;
    const int swzc = (c & 7) << 2;           // row&7 == c&7 for row=nt*16+c

    const int mnode = n0 + w * 16 + c;
    const int arow = (mnode < N) ? mnode : (N - 1);
    const float* aptr = nf + (size_t)arow * NODE_DIM + quad * 8;

    f32x4 c1[4];
    #pragma unroll
    for (int q = 0; q < 4; ++q) { c1[q][0]=0.f; c1[q][1]=0.f; c1[q][2]=0.f; c1[q][3]=0.f; }

    #pragma unroll 4
    for (int kt = 0; kt < 8; ++kt) {
        const float4 a01 = *(const float4*)(aptr + kt * 32);
        const float4 a23 = *(const float4*)(aptr + kt * 32 + 4);
        bf16x8 af;
        af[0]=f2bf(a01.x); af[1]=f2bf(a01.y); af[2]=f2bf(a01.z); af[3]=f2bf(a01.w);
        af[4]=f2bf(a23.x); af[5]=f2bf(a23.y); af[6]=f2bf(a23.z); af[7]=f2bf(a23.w);
        const int pch = (kt * 4 + quad) ^ swzc;
        #pragma unroll
        for (int nt = 0; nt < 4; ++nt) {
            const bf16x8 bfr = *(const bf16x8*)(fwL + (nt * 16 + c) * 256 + pch * 8);
            c1[nt] = __builtin_amdgcn_mfma_f32_16x16x32_bf16(af, bfr, c1[nt], 0, 0, 0);
        }
    }

    #pragma unroll
    for (int nt = 0; nt < 4; ++nt) {
        const float b = film_b[nt * 16 + c];
        c1[nt][0] += b; c1[nt][1] += b; c1[nt][2] += b; c1[nt][3] += b;
    }

    float sum[4], sq[4];
    #pragma unroll
    for (int rr = 0; rr < 4; ++rr) {
        sum[rr] = c1[0][rr] + c1[1][rr] + c1[2][rr] + c1[3][rr];
        sq[rr]  = c1[0][rr]*c1[0][rr] + c1[1][rr]*c1[1][rr]
                + c1[2][rr]*c1[2][rr] + c1[3][rr]*c1[3][rr];
    }
    #pragma unroll
    for (int off = 1; off < 16; off <<= 1) {
        #pragma unroll
        for (int rr = 0; rr < 4; ++rr) {
            sum[rr] += __shfl_xor(sum[rr], off, 64);
            sq[rr]  += __shfl_xor(sq[rr],  off, 64);
        }
    }
    float mu[4], inv[4];
    int gid[4];
    #pragma unroll
    for (int rr = 0; rr < 4; ++rr) {
        mu[rr] = sum[rr] * (1.0f / HID);
        float var = sq[rr] * (1.0f / HID) - mu[rr] * mu[rr];
        var = fmaxf(var, 0.f);
        inv[rr] = rsqrtf(var + LN_EPS);
        const int nn = n0 + w * 16 + quad * 4 + rr;
        gid[rr] = n2g[(nn < N) ? nn : (N - 1)];
    }

    #pragma unroll
    for (int rr = 0; rr < 4; ++rr) {
        const int nn = n0 + w * 16 + quad * 4 + rr;
        if (nn >= N) continue;
        #pragma unroll
        for (int nt = 0; nt < 4; ++nt) {
            const int col = nt * 16 + c;
            const float ga = gamma[gid[rr] * HID + col];
            const float be = beta[gid[rr] * HID + col];
            const float v = fmaxf(ga * ((c1[nt][rr] - mu[rr]) * inv[rr]) + be, 0.f);
            const int q = __float2int_rn(v * H_SCALE);
            h_out[(size_t)nn * HID + col] = (unsigned short)min(q, 65535);
        }
    }
}

// ---------------------------------------------------------------------------
// bin_aggregate_fused: one block per 128-node window, 512 threads.
//  - cnt from bin_fill, base = bin*CAP (fixed-capacity, unordered entries).
//  - acc as u64 per feat-PAIR: one uint gather + one ds_add_u64 per TWO
//    edges per wave-instruction. deg rides at bit 23 of even feat words.
//  - part chunk staged into LDS; epilogue = fused final linear (MFMA) ->
//    bias -> relu -> deg-mask -> out.
// ---------------------------------------------------------------------------
__global__ __launch_bounds__(512) void bin_aggregate_fused(
    const int* __restrict__ part, const int* __restrict__ bin_fill,
    const unsigned int* __restrict__ h32,   // [N][32] uint (2 fixed ushorts)
    const short* __restrict__ wlin_bf,      // [128 o][64 k] bf16
    const float* __restrict__ lin_b,
    float* __restrict__ out, int N)
{
    __shared__ unsigned long long acc64[WINDOW * 32];  // 32 KB
    __shared__ int pbuf[1024];                          // 4 KB chunk of part
    __shared__ int degl[WINDOW];
    const int b = blockIdx.x;
    const int t = threadIdx.x;
    const int base = b * BIN_CAP;
    const int cnt  = min(bin_fill[b], BIN_CAP);
    const int w0 = b << BIN_SHIFT;

    {
        int4* a4 = (int4*)acc64;
        const int4 z = make_int4(0, 0, 0, 0);
        #pragma unroll
        for (int i = 0; i < (WINDOW * 64 / 4) / 512; ++i)
            a4[i * 512 + t] = z;
    }
    __syncthreads();

    const int lane = t & 63;
    const int wv = t >> 6;        // 0..7
    const int eh = lane >> 5;     // half: edge slot 0/1
    const int u = lane & 31;      // uint feat-pair index

    for (int c0 = 0; c0 < cnt; c0 += 1024) {
        const int csz = min(1024, cnt - c0);
        for (int i = t; i < csz; i += 512) pbuf[i] = part[base + c0 + i];
        __syncthreads();

        // 16 edges (8 pairs) per wave-iteration
        for (int i0 = wv * 16; i0 < csz; i0 += 128) {
            int v[8], dl[8];
            #pragma unroll
            for (int j = 0; j < 8; ++j) {
                const int idx = i0 + j * 2 + eh;
                v[j] = pbuf[(idx < csz) ? idx : 0];
                dl[j] = (idx < csz) ? (v[j] >> PACK_SHIFT) : -1;
            }
            unsigned int hv[8];
            #pragma unroll
            for (int j = 0; j < 8; ++j)
                hv[j] = h32[(size_t)(v[j] & SRC_MASK) * 32 + u];
            #pragma unroll
            for (int j = 0; j < 8; ++j) {
                if (dl[j] >= 0) {
                    const unsigned long long val =
                        ((unsigned long long)(hv[j] >> 16) << 32) |
                        (unsigned long long)((hv[j] & 0xFFFFu) + (1u << DEG_BIT));
                    atomicAdd(&acc64[(dl[j] << 5) + u], val);
                }
            }
        }
        __syncthreads();
    }

    // extract deg per row (even word 0 carries the count)
    const int* acci = (const int*)acc64;
    for (int i = t; i < WINDOW; i += 512)
        degl[i] = ((unsigned int)acci[i << 6]) >> DEG_BIT;
    __syncthreads();

    // ---- fused final linear: 2 tiles of 64 rows, 4 waves each -----------
    const int c = lane & 15;
    const int quad = lane >> 4;
    const int wi = wv & 3;      // wave's 16-row slice within tile
    const int ti = wv >> 2;     // tile 0/1

    const int la = ti * 64 + wi * 16 + c;                 // A-load local row
    const int dga = degl[la];
    const float inva = (dga > 0) ? (1.f / (H_SCALE * (float)dga)) : 0.f;

    f32x4 c2[8];
    #pragma unroll
    for (int q = 0; q < 8; ++q) { c2[q][0]=0.f; c2[q][1]=0.f; c2[q][2]=0.f; c2[q][3]=0.f; }

    #pragma unroll
    for (int kt = 0; kt < 2; ++kt) {
        const int4 q0 = *(const int4*)&acci[(la << 6) + kt * 32 + quad * 8];
        const int4 q1 = *(const int4*)&acci[(la << 6) + kt * 32 + quad * 8 + 4];
        bf16x8 af;
        af[0] = f2bf((float)(q0.x & SUM_MASK) * inva);
        af[1] = f2bf((float)(q0.y & SUM_MASK) * inva);
        af[2] = f2bf((float)(q0.z & SUM_MASK) * inva);
        af[3] = f2bf((float)(q0.w & SUM_MASK) * inva);
        af[4] = f2bf((float)(q1.x & SUM_MASK) * inva);
        af[5] = f2bf((float)(q1.y & SUM_MASK) * inva);
        af[6] = f2bf((float)(q1.z & SUM_MASK) * inva);
        af[7] = f2bf((float)(q1.w & SUM_MASK) * inva);
        #pragma unroll
        for (int nt = 0; nt < 8; ++nt) {
            const bf16x8 bfr = *(const bf16x8*)(wlin_bf + (nt * 16 + c) * HID + kt * 32 + quad * 8);
            c2[nt] = __builtin_amdgcn_mfma_f32_16x16x32_bf16(af, bfr, c2[nt], 0, 0, 0);
        }
    }

    #pragma unroll
    for (int nt = 0; nt < 8; ++nt) {
        const float lb = lin_b[nt * 16 + c];
        #pragma unroll
        for (int reg = 0; reg < 4; ++reg) {
            const int lrow = ti * 64 + wi * 16 + quad * 4 + reg;  // C row
            const int nn = w0 + lrow;
            if (nn < N) {
                const float mask = (degl[lrow] > 0) ? 1.f : 0.f;
                out[(size_t)nn * OUT_DIM + nt * 16 + c] =
                    mask * fmaxf(c2[nt][reg] + lb, 0.f);
            }
        }
    }
}

extern "C" void kernel_launch(void* const* d_in, const int* in_sizes, int n_in,
                              void* d_out, int out_size, void* d_ws, size_t ws_size,
                              hipStream_t stream) {
    const float* node_feats = (const float*)d_in[0];
    const float* cond_feats = (const float*)d_in[1];
    const float* cond_w_v   = (const float*)d_in[2];
    const float* cond_w_g   = (const float*)d_in[3];
    const float* cond_b     = (const float*)d_in[4];
    const float* film_w     = (const float*)d_in[5];
    const float* film_b     = (const float*)d_in[6];
    const float* lin_w_v    = (const float*)d_in[7];
    const float* lin_w_g    = (const float*)d_in[8];
    const float* lin_b      = (const float*)d_in[9];
    const int* edge_index   = (const int*)d_in[10];
    const int* node2graph   = (const int*)d_in[11];

    const int N = in_sizes[0] / NODE_DIM;     // 100000
    const int B = in_sizes[1] / COND_DIM;     // 64
    const int E = in_sizes[10] / 2;           // 1600000
    const int nbin = (N + WINDOW - 1) >> BIN_SHIFT;   // 782

    auto align_up = [](size_t x) { return (x + 255) & ~(size_t)255; };
    char* ws = (char*)d_ws;
    size_t off = 0;
    int* bin_fill   = (int*)(ws + off); off += align_up(MAXBIN * 4);
    int* part       = (int*)(ws + off); off += align_up((size_t)MAXBIN * BIN_CAP * 4);
    unsigned short* h_buf = (unsigned short*)(ws + off); off += align_up((size_t)N * HID * 2);
    float* gamma    = (float*)(ws + off); off += align_up((size_t)B * HID * 4);
    float* beta     = (float*)(ws + off); off += align_up((size_t)B * HID * 4);
    short* wlin_bf  = (short*)(ws + off); off += align_up((size_t)OUT_DIM * HID * 2);
    short* fw_bf    = (short*)(ws + off); off += align_up((size_t)HID * NODE_DIM * 2);

    prep<<<130, 256, 0, stream>>>(cond_feats, cond_w_v, cond_w_g, cond_b,
                                  lin_w_v, lin_w_g, film_w,
                                  gamma, beta, wlin_bf, fw_bf, bin_fill, N, B);

    const int G_film = (N + 127) / 128;               // 782
    const int G_scat = (E + 8191) / 8192;             // 196
    fused_phase1<<<G_scat + G_film, 512, 0, stream>>>(
        node_feats, fw_bf, film_b, gamma, beta, node2graph, h_buf,
        edge_index, bin_fill, part, N, E, G_scat);

    bin_aggregate_fused<<<nbin, 512, 0, stream>>>(
        part, bin_fill, (const unsigned int*)h_buf,
        wlin_bf, lin_b, (float*)d_out, N);
}

// Round 13
// 273.147 us; speedup vs baseline: 1.0288x; 1.0288x over previous
//
#include <hip/hip_runtime.h>
#include <hip/hip_bf16.h>

#define NODE_DIM 256
#define COND_DIM 512
#define OUT_DIM  128
#define HID      64
#define LN_EPS   1e-5f

// dst-bin partition: windows of 128 nodes -> nbin = ceil(N/128) (=782)
#define BIN_SHIFT 7
#define WINDOW    128
#define MAXBIN    1024

// fixed-capacity bins: no prefix scan needed. mean fill 2048, sd ~45 over
// 782 bins -> CAP=4096 is ~45 sigma of headroom. part = MAXBIN*CAP*4B = 16MB.
#define BIN_CAP   4096

// part entry packed: (local_row << 20) | src   (src < 2^17, local_row < 128)
#define PACK_SHIFT 20
#define SRC_MASK   0xFFFFF

// h stored fixed-point ushort (x512). LDS accumulator is u64 per feat-pair:
// low 32 = sum(feat even) + deg<<23, high 32 = sum(feat odd).
// All-int LDS atomics only (fp LDS atomic = CAS loop, round-3 lesson: 696us).
#define H_SCALE   512.f
#define DEG_BIT   23
#define SUM_MASK  ((1 << DEG_BIT) - 1)

typedef __attribute__((ext_vector_type(8))) short bf16x8;
typedef __attribute__((ext_vector_type(4))) float f32x4;

__device__ __forceinline__ short f2bf(float f) {
    __hip_bfloat16 h = __float2bfloat16(f);
    return *reinterpret_cast<short*>(&h);
}

// ---------------------------------------------------------------------------
// prep (grid 130):
//  blocks 0..127 : cond projection output o (weight-normed) -> gamma/beta
//  block 128     : weight-norm lin_w_v rows -> wlin_bf [128 o][64 k] bf16
//  block 129     : film_w -> fw_bf [64 h][256 k] bf16 ; zero bin_fill
// ---------------------------------------------------------------------------
__global__ __launch_bounds__(256) void prep(
    const float* __restrict__ cond_feats,
    const float* __restrict__ cond_w_v,
    const float* __restrict__ cond_w_g,
    const float* __restrict__ cond_b,
    const float* __restrict__ lin_w_v,
    const float* __restrict__ lin_w_g,
    const float* __restrict__ film_w,
    float* __restrict__ gamma, float* __restrict__ beta,
    short* __restrict__ wlin_bf, short* __restrict__ fw_bf,
    int* __restrict__ bin_fill, int N, int B)
{
    const int t = threadIdx.x;
    const int bid = blockIdx.x;
    if (bid == 128) {
        if (t < OUT_DIM) {
            const int o = t;
            float nrm = 0.f;
            float w[HID];
            #pragma unroll
            for (int k = 0; k < HID; ++k) {
                w[k] = lin_w_v[o * HID + k];
                nrm += w[k] * w[k];
            }
            const float s = lin_w_g[o] * rsqrtf(nrm);
            #pragma unroll
            for (int k = 0; k < HID; ++k) wlin_bf[o * HID + k] = f2bf(w[k] * s);
        }
        return;
    }
    if (bid == 129) {
        #pragma unroll
        for (int s = 0; s < MAXBIN / 256; ++s) bin_fill[t + s * 256] = 0;
        for (int idx = t; idx < HID * NODE_DIM; idx += 256)
            fw_bf[idx] = f2bf(film_w[idx]);
        return;
    }
    const int o = bid;
    const int lane = t & 63;
    const int wv = t >> 6;
    __shared__ float s_cp[64];
    __shared__ float s_nrm;
    float wreg[COND_DIM / 64];
    #pragma unroll
    for (int j = 0; j < COND_DIM / 64; ++j)
        wreg[j] = cond_w_v[o * COND_DIM + j * 64 + lane];
    float nr = 0.f;
    #pragma unroll
    for (int j = 0; j < COND_DIM / 64; ++j) nr += wreg[j] * wreg[j];
    #pragma unroll
    for (int off = 32; off > 0; off >>= 1) nr += __shfl_xor(nr, off, 64);
    if (t == 0) s_nrm = nr;
    for (int b = wv; b < 64; b += 4) {
        float a = 0.f;
        #pragma unroll
        for (int j = 0; j < COND_DIM / 64; ++j)
            a += wreg[j] * cond_feats[b * COND_DIM + j * 64 + lane];
        #pragma unroll
        for (int off = 32; off > 0; off >>= 1) a += __shfl_xor(a, off, 64);
        if (lane == 0) s_cp[b] = a;
    }
    __syncthreads();
    if (t < 64) {
        const float scale = cond_w_g[o] * rsqrtf(s_nrm);
        const float cp = scale * s_cp[t] + cond_b[o];
        if (o < HID) gamma[t * HID + o] = cp + 1.0f;
        else         beta[t * HID + (o - HID)] = cp;
    }
}

// ---------------------------------------------------------------------------
// fused_phase1 (round-11 measured-best config): 256-thread blocks, role
// split (scatter first, then film).
//  scatter blocks: LDS hist over 8192 edges -> one returning atomic per
//    (block,bin) -> scatter packed (dl<<20|src) into part[bin*CAP...].
//  film blocks: 64 nodes. fw_bf staged in LDS (32KB, XOR-swizzled) -- fw is
//    L1-sized and evicted by the nf stream; LDS staging was +19% (r11).
//    A-fragments direct from global.
// ---------------------------------------------------------------------------
__global__ __launch_bounds__(256) void fused_phase1(
    const float* __restrict__ nf,
    const short* __restrict__ fw_bf,      // [64 h][256 k]
    const float* __restrict__ film_b,
    const float* __restrict__ gamma, const float* __restrict__ beta,
    const int*  __restrict__ n2g,
    unsigned short* __restrict__ h_out,   // [N][64] fixed-point x512
    const int* __restrict__ ei,
    int* __restrict__ bin_fill,
    int* __restrict__ part,
    int N, int E, int G_scat)
{
    __shared__ int smem[8192];            // 32 KB, aliased per role
    const int t = threadIdx.x;
    const int bid = blockIdx.x;

    if (bid < G_scat) {
        // ---------------- scatter block: 8192 edges ----------------------
        int* hist      = smem;            // [1024]
        int* chunkbase = smem + 1024;     // [1024]
        int* cursor    = smem + 2048;     // [1024]
        #pragma unroll
        for (int s = 0; s < 4; ++s) {
            hist[t + s * 256] = 0;
            cursor[t + s * 256] = 0;
        }
        const int base = bid * 8192;

        int4 dr[8];
        bool full[8];
        #pragma unroll
        for (int j = 0; j < 8; ++j) {
            const int e0 = base + j * 1024 + t * 4;
            full[j] = (e0 + 3 < E);
            if (full[j]) dr[j] = *(const int4*)(ei + E + e0);
        }
        __syncthreads();

        #pragma unroll
        for (int j = 0; j < 8; ++j) {
            if (full[j]) {
                atomicAdd(&hist[dr[j].x >> BIN_SHIFT], 1);
                atomicAdd(&hist[dr[j].y >> BIN_SHIFT], 1);
                atomicAdd(&hist[dr[j].z >> BIN_SHIFT], 1);
                atomicAdd(&hist[dr[j].w >> BIN_SHIFT], 1);
            } else {
                const int e0 = base + j * 1024 + t * 4;
                for (int k = 0; k < 4; ++k) {
                    const int e = e0 + k;
                    if (e < E) atomicAdd(&hist[ei[E + e] >> BIN_SHIFT], 1);
                }
            }
        }
        __syncthreads();
        #pragma unroll
        for (int s = 0; s < 4; ++s) {
            const int x = t + s * 256;
            const int c = hist[x];
            chunkbase[x] = (c > 0) ? atomicAdd(&bin_fill[x], c) : 0;
        }
        __syncthreads();

        #pragma unroll
        for (int j = 0; j < 8; ++j) {
            const int e0 = base + j * 1024 + t * 4;
            if (full[j]) {
                const int4 d4 = dr[j];
                const int4 s4 = *(const int4*)(ei + e0);
                int b, r;
                b = d4.x >> BIN_SHIFT; r = chunkbase[b] + atomicAdd(&cursor[b], 1);
                if (r < BIN_CAP) part[b * BIN_CAP + r] = ((d4.x & (WINDOW - 1)) << PACK_SHIFT) | s4.x;
                b = d4.y >> BIN_SHIFT; r = chunkbase[b] + atomicAdd(&cursor[b], 1);
                if (r < BIN_CAP) part[b * BIN_CAP + r] = ((d4.y & (WINDOW - 1)) << PACK_SHIFT) | s4.y;
                b = d4.z >> BIN_SHIFT; r = chunkbase[b] + atomicAdd(&cursor[b], 1);
                if (r < BIN_CAP) part[b * BIN_CAP + r] = ((d4.z & (WINDOW - 1)) << PACK_SHIFT) | s4.z;
                b = d4.w >> BIN_SHIFT; r = chunkbase[b] + atomicAdd(&cursor[b], 1);
                if (r < BIN_CAP) part[b * BIN_CAP + r] = ((d4.w & (WINDOW - 1)) << PACK_SHIFT) | s4.w;
            } else {
                for (int k = 0; k < 4; ++k) {
                    const int e = e0 + k;
                    if (e < E) {
                        const int d = ei[E + e];
                        const int b = d >> BIN_SHIFT;
                        const int r = chunkbase[b] + atomicAdd(&cursor[b], 1);
                        if (r < BIN_CAP)
                            part[b * BIN_CAP + r] =
                                ((d & (WINDOW - 1)) << PACK_SHIFT) | ei[e];
                    }
                }
            }
        }
        return;
    }

    // ---------------- film block ----------------------------------------
    unsigned short* fwL = (unsigned short*)smem;   // [64][256] bf16, swizzled
    const int film_id = bid - G_scat;
    const int n0 = film_id * 64;
    if (n0 >= N) return;

    // stage fw_bf -> LDS: 2048 16B chunks, coalesced, chunk-XOR swizzle
    #pragma unroll
    for (int i = 0; i < 8; ++i) {
        const int g = i * 256 + t;            // global chunk id
        const int row = g >> 5;
        const int cc = g & 31;
        const int p = cc ^ ((row & 7) << 2);  // physical chunk
        *(bf16x8*)(fwL + row * 256 + p * 8) =
            *(const bf16x8*)(fw_bf + row * 256 + cc * 8);
    }
    __syncthreads();

    const int w = t >> 6;
    const int lane = t & 63;
    const int c = lane & 15;
    const int quad = lane >> 4;
    const int swzc = (c & 7) << 2;           // row&7 == c&7 for row=nt*16+c

    const int mnode = n0 + w * 16 + c;
    const int arow = (mnode < N) ? mnode : (N - 1);
    const float* aptr = nf + (size_t)arow * NODE_DIM + quad * 8;

    f32x4 c1[4];
    #pragma unroll
    for (int q = 0; q < 4; ++q) { c1[q][0]=0.f; c1[q][1]=0.f; c1[q][2]=0.f; c1[q][3]=0.f; }

    #pragma unroll 4
    for (int kt = 0; kt < 8; ++kt) {
        const float4 a01 = *(const float4*)(aptr + kt * 32);
        const float4 a23 = *(const float4*)(aptr + kt * 32 + 4);
        bf16x8 af;
        af[0]=f2bf(a01.x); af[1]=f2bf(a01.y); af[2]=f2bf(a01.z); af[3]=f2bf(a01.w);
        af[4]=f2bf(a23.x); af[5]=f2bf(a23.y); af[6]=f2bf(a23.z); af[7]=f2bf(a23.w);
        const int pch = (kt * 4 + quad) ^ swzc;
        #pragma unroll
        for (int nt = 0; nt < 4; ++nt) {
            const bf16x8 bfr = *(const bf16x8*)(fwL + (nt * 16 + c) * 256 + pch * 8);
            c1[nt] = __builtin_amdgcn_mfma_f32_16x16x32_bf16(af, bfr, c1[nt], 0, 0, 0);
        }
    }

    #pragma unroll
    for (int nt = 0; nt < 4; ++nt) {
        const float b = film_b[nt * 16 + c];
        c1[nt][0] += b; c1[nt][1] += b; c1[nt][2] += b; c1[nt][3] += b;
    }

    float sum[4], sq[4];
    #pragma unroll
    for (int rr = 0; rr < 4; ++rr) {
        sum[rr] = c1[0][rr] + c1[1][rr] + c1[2][rr] + c1[3][rr];
        sq[rr]  = c1[0][rr]*c1[0][rr] + c1[1][rr]*c1[1][rr]
                + c1[2][rr]*c1[2][rr] + c1[3][rr]*c1[3][rr];
    }
    #pragma unroll
    for (int off = 1; off < 16; off <<= 1) {
        #pragma unroll
        for (int rr = 0; rr < 4; ++rr) {
            sum[rr] += __shfl_xor(sum[rr], off, 64);
            sq[rr]  += __shfl_xor(sq[rr],  off, 64);
        }
    }
    float mu[4], inv[4];
    int gid[4];
    #pragma unroll
    for (int rr = 0; rr < 4; ++rr) {
        mu[rr] = sum[rr] * (1.0f / HID);
        float var = sq[rr] * (1.0f / HID) - mu[rr] * mu[rr];
        var = fmaxf(var, 0.f);
        inv[rr] = rsqrtf(var + LN_EPS);
        const int nn = n0 + w * 16 + quad * 4 + rr;
        gid[rr] = n2g[(nn < N) ? nn : (N - 1)];
    }

    #pragma unroll
    for (int rr = 0; rr < 4; ++rr) {
        const int nn = n0 + w * 16 + quad * 4 + rr;
        if (nn >= N) continue;
        #pragma unroll
        for (int nt = 0; nt < 4; ++nt) {
            const int col = nt * 16 + c;
            const float ga = gamma[gid[rr] * HID + col];
            const float be = beta[gid[rr] * HID + col];
            const float v = fmaxf(ga * ((c1[nt][rr] - mu[rr]) * inv[rr]) + be, 0.f);
            const int q = __float2int_rn(v * H_SCALE);
            h_out[(size_t)nn * HID + col] = (unsigned short)min(q, 65535);
        }
    }
}

// ---------------------------------------------------------------------------
// bin_aggregate_fused v4: one block per 128-node window, 512 threads.
//  GATHER WIDENED: 16 lanes x uint2 (8B) per edge -> ONE gather instruction
//  covers FOUR edges (vs two) -- same 128B line per edge, half the gather
//  instruction count, 2x lines in flight. ds_add_u64 count unchanged (fixed
//  by data volume): each lane now issues 2 ds_adds per edge-quad.
//  deg rides at bit 23 of every u64's low word; epilogue = fused final
//  linear (MFMA) -> bias -> relu -> deg-mask -> out.
// ---------------------------------------------------------------------------
__global__ __launch_bounds__(512) void bin_aggregate_fused(
    const int* __restrict__ part, const int* __restrict__ bin_fill,
    const unsigned int* __restrict__ h32,   // [N][32] uint (2 fixed ushorts)
    const short* __restrict__ wlin_bf,      // [128 o][64 k] bf16
    const float* __restrict__ lin_b,
    float* __restrict__ out, int N)
{
    __shared__ unsigned long long acc64[WINDOW * 32];  // 32 KB
    __shared__ int pbuf[1024];                          // 4 KB chunk of part
    __shared__ int degl[WINDOW];
    const int b = blockIdx.x;
    const int t = threadIdx.x;
    const int base = b * BIN_CAP;
    const int cnt  = min(bin_fill[b], BIN_CAP);
    const int w0 = b << BIN_SHIFT;

    {
        int4* a4 = (int4*)acc64;
        const int4 z = make_int4(0, 0, 0, 0);
        #pragma unroll
        for (int i = 0; i < (WINDOW * 64 / 4) / 512; ++i)
            a4[i * 512 + t] = z;
    }
    __syncthreads();

    const int lane = t & 63;
    const int wv = t >> 6;        // 0..7
    const int eq = lane >> 4;     // edge slot 0..3
    const int u2 = lane & 15;     // u64-pair index (covers u64s 2u2, 2u2+1)

    for (int c0 = 0; c0 < cnt; c0 += 1024) {
        const int csz = min(1024, cnt - c0);
        for (int i = t; i < csz; i += 512) pbuf[i] = part[base + c0 + i];
        __syncthreads();

        // 32 edges (8 quads) per wave-iteration
        for (int i0 = wv * 32; i0 < csz; i0 += 256) {
            int v[8], dl[8];
            #pragma unroll
            for (int j = 0; j < 8; ++j) {
                const int idx = i0 + j * 4 + eq;
                v[j] = pbuf[(idx < csz) ? idx : 0];
                dl[j] = (idx < csz) ? (v[j] >> PACK_SHIFT) : -1;
            }
            uint2 hv[8];
            #pragma unroll
            for (int j = 0; j < 8; ++j)
                hv[j] = *(const uint2*)(h32 + (size_t)(v[j] & SRC_MASK) * 32 + u2 * 2);
            #pragma unroll
            for (int j = 0; j < 8; ++j) {
                if (dl[j] >= 0) {
                    const unsigned long long v0 =
                        ((unsigned long long)(hv[j].x >> 16) << 32) |
                        (unsigned long long)((hv[j].x & 0xFFFFu) + (1u << DEG_BIT));
                    const unsigned long long v1 =
                        ((unsigned long long)(hv[j].y >> 16) << 32) |
                        (unsigned long long)((hv[j].y & 0xFFFFu) + (1u << DEG_BIT));
                    atomicAdd(&acc64[(dl[j] << 5) + u2 * 2], v0);
                    atomicAdd(&acc64[(dl[j] << 5) + u2 * 2 + 1], v1);
                }
            }
        }
        __syncthreads();
    }

    // extract deg per row (u64 0's low word carries the count)
    const int* acci = (const int*)acc64;
    for (int i = t; i < WINDOW; i += 512)
        degl[i] = ((unsigned int)acci[i << 6]) >> DEG_BIT;
    __syncthreads();

    // ---- fused final linear: 2 tiles of 64 rows, 4 waves each -----------
    const int c = lane & 15;
    const int quad = lane >> 4;
    const int wi = wv & 3;      // wave's 16-row slice within tile
    const int ti = wv >> 2;     // tile 0/1

    const int la = ti * 64 + wi * 16 + c;                 // A-load local row
    const int dga = degl[la];
    const float inva = (dga > 0) ? (1.f / (H_SCALE * (float)dga)) : 0.f;

    f32x4 c2[8];
    #pragma unroll
    for (int q = 0; q < 8; ++q) { c2[q][0]=0.f; c2[q][1]=0.f; c2[q][2]=0.f; c2[q][3]=0.f; }

    #pragma unroll
    for (int kt = 0; kt < 2; ++kt) {
        const int4 q0 = *(const int4*)&acci[(la << 6) + kt * 32 + quad * 8];
        const int4 q1 = *(const int4*)&acci[(la << 6) + kt * 32 + quad * 8 + 4];
        bf16x8 af;
        af[0] = f2bf((float)(q0.x & SUM_MASK) * inva);
        af[1] = f2bf((float)(q0.y & SUM_MASK) * inva);
        af[2] = f2bf((float)(q0.z & SUM_MASK) * inva);
        af[3] = f2bf((float)(q0.w & SUM_MASK) * inva);
        af[4] = f2bf((float)(q1.x & SUM_MASK) * inva);
        af[5] = f2bf((float)(q1.y & SUM_MASK) * inva);
        af[6] = f2bf((float)(q1.z & SUM_MASK) * inva);
        af[7] = f2bf((float)(q1.w & SUM_MASK) * inva);
        #pragma unroll
        for (int nt = 0; nt < 8; ++nt) {
            const bf16x8 bfr = *(const bf16x8*)(wlin_bf + (nt * 16 + c) * HID + kt * 32 + quad * 8);
            c2[nt] = __builtin_amdgcn_mfma_f32_16x16x32_bf16(af, bfr, c2[nt], 0, 0, 0);
        }
    }

    #pragma unroll
    for (int nt = 0; nt < 8; ++nt) {
        const float lb = lin_b[nt * 16 + c];
        #pragma unroll
        for (int reg = 0; reg < 4; ++reg) {
            const int lrow = ti * 64 + wi * 16 + quad * 4 + reg;  // C row
            const int nn = w0 + lrow;
            if (nn < N) {
                const float mask = (degl[lrow] > 0) ? 1.f : 0.f;
                out[(size_t)nn * OUT_DIM + nt * 16 + c] =
                    mask * fmaxf(c2[nt][reg] + lb, 0.f);
            }
        }
    }
}

extern "C" void kernel_launch(void* const* d_in, const int* in_sizes, int n_in,
                              void* d_out, int out_size, void* d_ws, size_t ws_size,
                              hipStream_t stream) {
    const float* node_feats = (const float*)d_in[0];
    const float* cond_feats = (const float*)d_in[1];
    const float* cond_w_v   = (const float*)d_in[2];
    const float* cond_w_g   = (const float*)d_in[3];
    const float* cond_b     = (const float*)d_in[4];
    const float* film_w     = (const float*)d_in[5];
    const float* film_b     = (const float*)d_in[6];
    const float* lin_w_v    = (const float*)d_in[7];
    const float* lin_w_g    = (const float*)d_in[8];
    const float* lin_b      = (const float*)d_in[9];
    const int* edge_index   = (const int*)d_in[10];
    const int* node2graph   = (const int*)d_in[11];

    const int N = in_sizes[0] / NODE_DIM;     // 100000
    const int B = in_sizes[1] / COND_DIM;     // 64
    const int E = in_sizes[10] / 2;           // 1600000
    const int nbin = (N + WINDOW - 1) >> BIN_SHIFT;   // 782

    auto align_up = [](size_t x) { return (x + 255) & ~(size_t)255; };
    char* ws = (char*)d_ws;
    size_t off = 0;
    int* bin_fill   = (int*)(ws + off); off += align_up(MAXBIN * 4);
    int* part       = (int*)(ws + off); off += align_up((size_t)MAXBIN * BIN_CAP * 4);
    unsigned short* h_buf = (unsigned short*)(ws + off); off += align_up((size_t)N * HID * 2);
    float* gamma    = (float*)(ws + off); off += align_up((size_t)B * HID * 4);
    float* beta     = (float*)(ws + off); off += align_up((size_t)B * HID * 4);
    short* wlin_bf  = (short*)(ws + off); off += align_up((size_t)OUT_DIM * HID * 2);
    short* fw_bf    = (short*)(ws + off); off += align_up((size_t)HID * NODE_DIM * 2);

    prep<<<130, 256, 0, stream>>>(cond_feats, cond_w_v, cond_w_g, cond_b,
                                  lin_w_v, lin_w_g, film_w,
                                  gamma, beta, wlin_bf, fw_bf, bin_fill, N, B);

    const int G_film = (N + 63) / 64;                 // 1563
    const int G_scat = (E + 8191) / 8192;             // 196
    fused_phase1<<<G_scat + G_film, 256, 0, stream>>>(
        node_feats, fw_bf, film_b, gamma, beta, node2graph, h_buf,
        edge_index, bin_fill, part, N, E, G_scat);

    bin_aggregate_fused<<<nbin, 512, 0, stream>>>(
        part, bin_fill, (const unsigned int*)h_buf,
        wlin_bf, lin_b, (float*)d_out, N);
}